// Round 8
// baseline (539.027 us; speedup 1.0000x reference)
//
#include <hip/hip_runtime.h>
#include <math.h>

#if __has_builtin(__builtin_amdgcn_exp2f)
#define EXP2(x) __builtin_amdgcn_exp2f(x)
#else
#define EXP2(x) exp2f(x)
#endif

#define ALPHA_LRELU 0.2f
#define LOG2E 1.4426950408889634f
#define ESHIFT 6.0f
#define BIGM 1024.0f  // bit=0 -> exp2 arg < -1000 -> p = 0

constexpr int Bc = 2, Nn = 2048, Ff = 256, Hh = 8, Oo = 32;

typedef _Float16 f16;
typedef f16 f16x8 __attribute__((ext_vector_type(8)));
typedef f16 f16x4 __attribute__((ext_vector_type(4)));
typedef float f32x4 __attribute__((ext_vector_type(4)));
typedef unsigned long long u64;
typedef unsigned u32;

__global__ __launch_bounds__(256) void zero_kernel(float* __restrict__ p) {
    p[blockIdx.x * 256 + threadIdx.x] = 0.f;
}

// ---------------------------------------------------------------------------
// adj -> bitmask (u64 words; u32 sub-words index 32-j chunks little-endian)
// ---------------------------------------------------------------------------
__global__ __launch_bounds__(256) void pack_kernel(
    const int* __restrict__ adj, u64* __restrict__ mask) {
    int idx = blockIdx.x * 256 + threadIdx.x;
    u64 b = __ballot(adj[idx] != 0);
    if ((threadIdx.x & 63) == 0) mask[idx >> 6] = b;
}

// ---------------------------------------------------------------------------
// Weights: WT[y][c][k] f16 (k contiguous), y = l*2+stage.
// ---------------------------------------------------------------------------
__global__ __launch_bounds__(256) void wt_kernel(
    const float* __restrict__ W_heads, const float* __restrict__ W_out,
    f16* __restrict__ WT) {
    int t = threadIdx.x;
    int y = blockIdx.y;
    int l = y >> 1, st = y & 1;
    int c = blockIdx.x * 4 + (t >> 6);
    int k0 = (t & 63) * 4;
    const float* src;
    int stride;
    if (st == 0) {
        src = W_heads + (((size_t)l * Hh + (c >> 5)) * Ff) * Oo + (c & 31);
        stride = Oo;
    } else {
        src = W_out + (size_t)l * Ff * Ff + c;
        stride = Ff;
    }
    f16x4 v;
#pragma unroll
    for (int i = 0; i < 4; ++i) v[i] = (f16)src[(size_t)(k0 + i) * stride];
    *(f16x4*)&WT[((size_t)y * Ff + c) * Ff + k0] = v;
}

// ---------------------------------------------------------------------------
// MFMA GEMM, wave-private 16 rows x 16 cols, grid (64, 16) -> 4096 waves
// (16 waves/CU). Prefetch-1. Fused epilogue: CT f16 [bg][o][n] + s1/s2.
// ---------------------------------------------------------------------------
__global__ __launch_bounds__(256) void gemm_wave(
    const float* __restrict__ A, const f16* __restrict__ WT,
    const float* __restrict__ pa, f16* __restrict__ CT,
    float* __restrict__ s1, float* __restrict__ s2,
    int G, int Ofull, int oshift) {
    int t = threadIdx.x;
    int w = t >> 6, lane = t & 63;
    int am = lane & 15, aq = lane >> 4;
    int m0 = blockIdx.x * 64 + w * 16;
    int colb = blockIdx.y * 16;

    const float* aptr = A + (size_t)(m0 + am) * Ff + aq * 8;
    const f16* bp0 = WT + (size_t)(colb + am) * Ff + aq * 8;

    f32x4 acc0 = {0.f, 0.f, 0.f, 0.f};
    f32x4 xa0 = *(const f32x4*)aptr;
    f32x4 xa1 = *(const f32x4*)(aptr + 4);
    f16x8 xb0 = *(const f16x8*)bp0;

    for (int k0 = 0; k0 < Ff; k0 += 32) {
        int kn = (k0 + 32 < Ff) ? k0 + 32 : 0;
        f32x4 na0 = *(const f32x4*)(aptr + kn);
        f32x4 na1 = *(const f32x4*)(aptr + kn + 4);
        f16x8 nb0 = *(const f16x8*)(bp0 + kn);
        f16x8 af;
#pragma unroll
        for (int i = 0; i < 4; ++i) { af[i] = (f16)xa0[i]; af[4 + i] = (f16)xa1[i]; }
        acc0 = __builtin_amdgcn_mfma_f32_16x16x32_f16(af, xb0, acc0, 0, 0, 0);
        xa0 = na0; xa1 = na1; xb0 = nb0;
    }

    // ---- epilogue ----
    int b = m0 >> 11;
    int nn0 = (m0 & 2047) + aq * 4;
    int g = colb >> oshift;  // 16 cols always within one g
    size_t bg = (size_t)b * G + g;
    int o0 = (colb & (Ofull - 1)) + am;

    f16x4 c40;
#pragma unroll
    for (int e = 0; e < 4; ++e) c40[e] = (f16)acc0[e];
    *(f16x4*)&CT[(bg * Ofull + o0) * Nn + nn0] = c40;

    const float* a1p = pa + 2 * (size_t)g * Ofull;
    float a10 = a1p[o0];
    float a20 = a1p[Ofull + o0];
#pragma unroll
    for (int e = 0; e < 4; ++e) {
        float p1 = acc0[e] * a10;
        float p2 = acc0[e] * a20;
#pragma unroll
        for (int s = 1; s < 16; s <<= 1) {
            p1 += __shfl_xor(p1, s);
            p2 += __shfl_xor(p2, s);
        }
        if (am == 0) {
            size_t sidx = bg * Nn + nn0 + e;
            atomicAdd(&s1[sidx], p1);
            atomicAdd(&s2[sidx], p2);
        }
    }
}

// ---------------------------------------------------------------------------
// Attention, j-split x4: block = 16 rows x 32 cols; wave w covers the
// disjoint j-slice [w*512, (w+1)*512) -> no e-recompute inside a block,
// 2048 blocks (32 waves/CU). Private partial acc+l per wave; ONE barrier at
// the end; LDS combine; wave-0 epilogue. e-math identical to R7.
// ---------------------------------------------------------------------------
template <bool OUT>
__global__ __launch_bounds__(256) void attn_kernel(
    const f16* __restrict__ WhT, const float* __restrict__ s1,
    const float* __restrict__ s2, const u32* __restrict__ maskW,
    float* __restrict__ dst) {
    constexpr float C0 = -ESHIFT * LOG2E - BIGM;
    __shared__ float Ls[4][64];
    __shared__ float As[4][64][8];

    int t = threadIdx.x;
    int w = t >> 6, lane = t & 63;
    int am = lane & 15, aq = lane >> 4;
    int i0 = blockIdx.x * 16;
    int bz = blockIdx.z;
    int b = OUT ? bz : (bz >> 3);
    int colb = OUT ? blockIdx.y * 32 : 0;
    int dstcol = OUT ? colb : (bz & 7) * Oo;

    const f16* whT = WhT + ((size_t)bz * (OUT ? Ff : Oo) + colb) * Nn;
    const float* s2p = s2 + (size_t)bz * Nn + aq * 8;
    float s1v = s1[(size_t)bz * Nn + i0 + am];
    const u32* mrow = maskW + ((size_t)b * Nn + i0 + am) * (Nn / 32);

    const f16* bp0 = whT + (size_t)am * Nn + aq * 8;
    const f16* bp1 = whT + (size_t)(16 + am) * Nn + aq * 8;

    f32x4 acc0 = {0.f, 0.f, 0.f, 0.f}, acc1 = acc0;
    float lacc = 0.f;

    int cbeg = w * 16, cend = cbeg + 16;  // 16 chunks of 32 j per wave
    f16x8 xb0 = *(const f16x8*)(bp0 + cbeg * 32);
    f16x8 xb1 = *(const f16x8*)(bp1 + cbeg * 32);
    f32x4 xv0 = *(const f32x4*)(s2p + cbeg * 32);
    f32x4 xv1 = *(const f32x4*)(s2p + cbeg * 32 + 4);
    u32 xm = mrow[cbeg];

    for (int c = cbeg; c < cend; ++c) {
        int cn = (c + 1 < cend) ? c + 1 : cbeg;
        f16x8 nb0 = *(const f16x8*)(bp0 + cn * 32);
        f16x8 nb1 = *(const f16x8*)(bp1 + cn * 32);
        f32x4 nv0 = *(const f32x4*)(s2p + cn * 32);
        f32x4 nv1 = *(const f32x4*)(s2p + cn * 32 + 4);
        u32 nm = mrow[cn];

        u32 bits = (xm >> (aq * 8)) & 0xffu;
        f16x8 af;
#pragma unroll
        for (int k = 0; k < 8; ++k) {
            float xv = s1v + (k < 4 ? xv0[k] : xv1[k - 4]);
            float lr = fmaxf(xv, ALPHA_LRELU * xv);
            float bitf = (float)((bits >> k) & 1u);
            float p = EXP2(fmaf(bitf, BIGM, fmaf(lr, LOG2E, C0)));
            lacc += p;
            af[k] = (f16)p;
        }
        acc0 = __builtin_amdgcn_mfma_f32_16x16x32_f16(af, xb0, acc0, 0, 0, 0);
        acc1 = __builtin_amdgcn_mfma_f32_16x16x32_f16(af, xb1, acc1, 0, 0, 0);
        xb0 = nb0; xb1 = nb1; xv0 = nv0; xv1 = nv1; xm = nm;
    }

    // intra-wave l reduction across aq groups -> every lane holds l[am]
    lacc += __shfl_xor(lacc, 16);
    lacc += __shfl_xor(lacc, 32);

    Ls[w][lane] = lacc;
#pragma unroll
    for (int e = 0; e < 4; ++e) {
        As[w][lane][e] = acc0[e];
        As[w][lane][4 + e] = acc1[e];
    }
    __syncthreads();

    if (w == 0) {
        float lt = Ls[0][lane] + Ls[1][lane] + Ls[2][lane] + Ls[3][lane];
        f32x4 a0, a1;
#pragma unroll
        for (int e = 0; e < 4; ++e) {
            a0[e] = As[0][lane][e] + As[1][lane][e] + As[2][lane][e] + As[3][lane][e];
            a1[e] = As[0][lane][4 + e] + As[1][lane][4 + e] +
                    As[2][lane][4 + e] + As[3][lane][4 + e];
        }
#pragma unroll
        for (int e = 0; e < 4; ++e) {
            int r = aq * 4 + e;             // C/D: col=am, row=aq*4+e
            float li = __shfl(lt, r);       // lane r holds l[row r]
            float v0 = a0[e] / li, v1 = a1[e] / li;
            v0 = v0 > 0.f ? v0 : __expf(v0) - 1.f;
            v1 = v1 > 0.f ? v1 : __expf(v1) - 1.f;
            if (OUT) {
                v0 = v0 > 0.f ? v0 : __expf(v0) - 1.f;
                v1 = v1 > 0.f ? v1 : __expf(v1) - 1.f;
            }
            size_t base = ((size_t)b * Nn + i0 + r) * Ff + dstcol;
            dst[base + am] = v0;
            dst[base + 16 + am] = v1;
        }
    }
}

// ---------------------------------------------------------------------------
extern "C" void kernel_launch(void* const* d_in, const int* in_sizes, int n_in,
                              void* d_out, int out_size, void* d_ws, size_t ws_size,
                              hipStream_t stream) {
    const float* x = (const float*)d_in[0];
    const int* adj = (const int*)d_in[1];
    const float* W_heads = (const float*)d_in[2];
    const float* a_heads = (const float*)d_in[3];
    const float* W_out = (const float*)d_in[4];
    const float* a_out = (const float*)d_in[5];
    float* out = (float*)d_out;

    float* ws = (float*)d_ws;
    const size_t M = (size_t)Bc * Nn * Ff;  // 1,048,576
    float* h_cur = ws;                      // [B,N,F] fp32
    float* h_tmp = ws + M;                  // [B,N,F] fp32
    f16* WhT = (f16*)(ws + 2 * M);          // [B,G,O,N] f16
    u64* mask = (u64*)(ws + 2 * M + M / 2); // 1 MB
    f16* WT = (f16*)(ws + 2 * M + M / 2 + M / 4);  // 6*F*F f16
    float* sbuf = ws + 2 * M + M / 2 + M / 4 + 196608;
    const size_t SH = (size_t)Bc * Hh * Nn;  // 32768
    const size_t SO = (size_t)Bc * Nn;       // 4096
    const size_t SL = 2 * SH + 2 * SO;

    zero_kernel<<<(3 * SL) / 256, 256, 0, stream>>>(sbuf);
    pack_kernel<<<(Bc * Nn * Nn) / 256, 256, 0, stream>>>(adj, mask);
    wt_kernel<<<dim3(Ff / 4, 6), 256, 0, stream>>>(W_heads, W_out, WT);
    const u32* maskW = (const u32*)mask;

    for (int l = 0; l < 3; ++l) {
        const float* hin = (l == 0) ? x : h_cur;
        float* s1h = sbuf + l * SL;
        float* s2h = s1h + SH;
        float* s1o = s2h + SH;
        float* s2o = s1o + SO;

        // ---- head GAT: G=8, O=32 ----
        gemm_wave<<<dim3((Bc * Nn) / 64, Ff / 16), 256, 0, stream>>>(
            hin, WT + (size_t)(2 * l) * Ff * Ff,
            a_heads + (size_t)l * Hh * 2 * Oo, WhT, s1h, s2h, Hh, Oo, 5);
        attn_kernel<false><<<dim3(Nn / 16, 1, Bc * Hh), 256, 0, stream>>>(
            WhT, s1h, s2h, maskW, h_tmp);

        // ---- out GAT: G=1, O=F=256 ----
        gemm_wave<<<dim3((Bc * Nn) / 64, Ff / 16), 256, 0, stream>>>(
            h_tmp, WT + (size_t)(2 * l + 1) * Ff * Ff,
            a_out + (size_t)l * 2 * Ff, WhT, s1o, s2o, 1, Ff, 8);
        float* dstp = (l == 2) ? out : h_cur;
        attn_kernel<true><<<dim3(Nn / 16, Ff / 32, Bc), 256, 0, stream>>>(
            WhT, s1o, s2o, maskW, dstp);
    }
}

// Round 9
// 326.622 us; speedup vs baseline: 1.6503x; 1.6503x over previous
//
#include <hip/hip_runtime.h>
#include <math.h>

#if __has_builtin(__builtin_amdgcn_exp2f)
#define EXP2(x) __builtin_amdgcn_exp2f(x)
#else
#define EXP2(x) exp2f(x)
#endif

#define ALPHA_LRELU 0.2f
#define LOG2E 1.4426950408889634f
#define ESHIFT 6.0f
#define BIGM 1024.0f  // bit=0 -> exp2 arg < -1000 -> p = 0

constexpr int Bc = 2, Nn = 2048, Ff = 256, Hh = 8, Oo = 32;

typedef _Float16 f16;
typedef f16 f16x8 __attribute__((ext_vector_type(8)));
typedef f16 f16x4 __attribute__((ext_vector_type(4)));
typedef float f32x4 __attribute__((ext_vector_type(4)));
typedef unsigned long long u64;
typedef unsigned u32;

__global__ __launch_bounds__(256) void zero_kernel(float* __restrict__ p) {
    p[blockIdx.x * 256 + threadIdx.x] = 0.f;
}

// ---------------------------------------------------------------------------
// adj -> bitmask u64 [b][i][c64]
// ---------------------------------------------------------------------------
__global__ __launch_bounds__(256) void pack_kernel(
    const int* __restrict__ adj, u64* __restrict__ mask) {
    int idx = blockIdx.x * 256 + threadIdx.x;
    u64 b = __ballot(adj[idx] != 0);
    if ((threadIdx.x & 63) == 0) mask[idx >> 6] = b;
}

// ---------------------------------------------------------------------------
// mask transpose: maskT[b][c32][i] = maskW32[b][i][c32]  (1 u32 = 32 j-bits)
// -> per-chunk mask load in attention is 16 consecutive u32 (one line).
// ---------------------------------------------------------------------------
__global__ __launch_bounds__(256) void masktr_kernel(
    const u32* __restrict__ mw, u32* __restrict__ mt) {
    int idx = blockIdx.x * 256 + threadIdx.x;  // (b*64 + c)*2048 + i
    int i = idx & 2047;
    int c = (idx >> 11) & 63;
    int b = idx >> 17;
    mt[idx] = mw[((size_t)b * 2048 + i) * 64 + c];
}

// ---------------------------------------------------------------------------
// Weights -> B-fragment-packed f16: WTF[y][cg][c][lane*8+i] =
//   Wcat[col=cg*16+am][k=c*32+aq*8+i],  y = l*2+stage, lane = aq*16+am.
// ---------------------------------------------------------------------------
__global__ __launch_bounds__(256) void wt_kernel(
    const float* __restrict__ W_heads, const float* __restrict__ W_out,
    f16* __restrict__ WTF) {
    int t = threadIdx.x;
    int y = blockIdx.y;
    int l = y >> 1, st = y & 1;
    int col = blockIdx.x * 4 + (t >> 6);
    int k0 = (t & 63) * 4;
    const float* src;
    int stride;
    if (st == 0) {
        src = W_heads + (((size_t)l * Hh + (col >> 5)) * Ff) * Oo + (col & 31);
        stride = Oo;
    } else {
        src = W_out + (size_t)l * Ff * Ff + col;
        stride = Ff;
    }
    f16x4 v;
#pragma unroll
    for (int i = 0; i < 4; ++i) v[i] = (f16)src[(size_t)(k0 + i) * stride];
    int cg = col >> 4, am = col & 15;
    int c = k0 >> 5, aq = (k0 >> 3) & 3, i0 = k0 & 7;
    WTF += (((size_t)y * 16 + cg) * 8 + c) * 512 + (aq * 16 + am) * 8 + i0;
    *(f16x4*)WTF = v;
}

// ---------------------------------------------------------------------------
// Activation pack: fp32 A[4096][256] -> f16 A-frag order
//   Af[mt][c][lane*8+i] = A[mt*16+am][c*32+aq*8+i].  Scatter-read ONCE.
// ---------------------------------------------------------------------------
__global__ __launch_bounds__(256) void apack_kernel(
    const float* __restrict__ A, f16* __restrict__ Af) {
    int t = threadIdx.x;
    int lane = t & 63;
    int slot = blockIdx.x * 4 + (t >> 6);  // mt*8 + c
    int am = lane & 15, aq = lane >> 4;
    int mt = slot >> 3, c = slot & 7;
    const float* ap = A + ((size_t)mt * 16 + am) * Ff + c * 32 + aq * 8;
    f32x4 v0 = *(const f32x4*)ap;
    f32x4 v1 = *(const f32x4*)(ap + 4);
    f16x8 o;
#pragma unroll
    for (int i = 0; i < 4; ++i) { o[i] = (f16)v0[i]; o[4 + i] = (f16)v1[i]; }
    *(f16x8*)&Af[(size_t)slot * 512 + lane * 8] = o;
}

// ---------------------------------------------------------------------------
// Frag GEMM: both operands fully coalesced (1KB/wave loads). Wave = 16 rows
// x 16 cols, grid (64,16) -> 4096 waves. Epilogue writes WhFrag in attention
// B-frag order + s1/s2 atomics.
// ---------------------------------------------------------------------------
__global__ __launch_bounds__(256) void gemm_wave(
    const f16* __restrict__ Af, const f16* __restrict__ WTF,
    const float* __restrict__ pa, f16* __restrict__ WhFrag,
    float* __restrict__ s1, float* __restrict__ s2,
    int G, int Ofull, int oshift) {
    int t = threadIdx.x;
    int w = t >> 6, lane = t & 63;
    int am = lane & 15, aq = lane >> 4;
    int mt = blockIdx.x * 4 + w;   // 16-row tile id over B*N
    int colb = blockIdx.y * 16;

    const f16* ap = Af + (size_t)(mt * 8) * 512 + lane * 8;
    const f16* bp = WTF + (size_t)((colb >> 4) * 8) * 512 + lane * 8;

    f32x4 acc = {0.f, 0.f, 0.f, 0.f};
    f16x8 a0 = *(const f16x8*)ap;
    f16x8 b0 = *(const f16x8*)bp;
#pragma unroll
    for (int c = 0; c < 8; ++c) {
        int cn = (c + 1 < 8) ? c + 1 : 0;
        f16x8 an = *(const f16x8*)(ap + cn * 512);
        f16x8 bn = *(const f16x8*)(bp + cn * 512);
        acc = __builtin_amdgcn_mfma_f32_16x16x32_f16(a0, b0, acc, 0, 0, 0);
        a0 = an; b0 = bn;
    }

    // ---- epilogue: WhFrag write (B-frag order for attention) ----
    int m0 = mt * 16;
    int b = m0 >> 11;
    int nn0 = (m0 & 2047) + aq * 4;
    int cO = (m0 & 2047) >> 5;
    int aq_p = ((mt & 1) << 1) | (aq >> 1);
    int i0p = (aq & 1) << 2;
    int g = colb >> oshift;
    size_t bg = (size_t)b * G + g;
    int cg = (colb & (Ofull - 1)) >> 4;

    f16x4 c4;
#pragma unroll
    for (int e = 0; e < 4; ++e) c4[e] = (f16)acc[e];
    *(f16x4*)&WhFrag[(((bg * (Ofull >> 4) + cg) * 64 + cO) * 512) +
                     (aq_p * 16 + am) * 8 + i0p] = c4;

    // ---- s1/s2 partials ----
    int o0 = (colb & (Ofull - 1)) + am;
    const float* a1p = pa + 2 * (size_t)g * Ofull;
    float a10 = a1p[o0];
    float a20 = a1p[Ofull + o0];
#pragma unroll
    for (int e = 0; e < 4; ++e) {
        float p1 = acc[e] * a10;
        float p2 = acc[e] * a20;
#pragma unroll
        for (int s = 1; s < 16; s <<= 1) {
            p1 += __shfl_xor(p1, s);
            p2 += __shfl_xor(p2, s);
        }
        if (am == 0) {
            size_t sidx = bg * Nn + nn0 + e;
            atomicAdd(&s1[sidx], p1);
            atomicAdd(&s2[sidx], p2);
        }
    }
}

// ---------------------------------------------------------------------------
// Attention: e-phase in registers (R7 math), B-frags COALESCED from WhFrag,
// mask from maskT (1 line/chunk). Wave = 16 rows x 32 cols, full j.
// Head grid (32,1,16); Out grid (32,8,2).
// ---------------------------------------------------------------------------
template <bool OUT>
__global__ __launch_bounds__(256) void attn_kernel(
    const f16* __restrict__ WhFrag, const float* __restrict__ s1,
    const float* __restrict__ s2, const u32* __restrict__ maskT,
    float* __restrict__ dst) {
    constexpr float C0 = -ESHIFT * LOG2E - BIGM;
    constexpr int NCG = OUT ? 16 : 2;  // col-groups per bg
    int t = threadIdx.x;
    int w = t >> 6, lane = t & 63;
    int am = lane & 15, aq = lane >> 4;
    int i0 = blockIdx.x * 64 + w * 16;
    int bz = blockIdx.z;
    int b = OUT ? bz : (bz >> 3);
    int cg0 = OUT ? blockIdx.y * 2 : 0;
    int dstcol = OUT ? cg0 * 16 : (bz & 7) * Oo;

    const f16* bp0 = WhFrag + ((size_t)bz * NCG + cg0) * 64 * 512 + lane * 8;
    const f16* bp1 = bp0 + 64 * 512;
    const float* s2p = s2 + (size_t)bz * Nn + aq * 8;
    float s1v = s1[(size_t)bz * Nn + i0 + am];
    const u32* mtp = maskT + (size_t)b * 64 * 2048 + i0 + am;

    f32x4 acc0 = {0.f, 0.f, 0.f, 0.f}, acc1 = acc0;
    float lacc = 0.f;

    f16x8 xb0 = *(const f16x8*)bp0;
    f16x8 xb1 = *(const f16x8*)bp1;
    f32x4 xv0 = *(const f32x4*)s2p;
    f32x4 xv1 = *(const f32x4*)(s2p + 4);
    u32 xm = mtp[0];

    for (int c = 0; c < 64; ++c) {
        int cn = (c + 1 < 64) ? c + 1 : 0;
        f16x8 nb0 = *(const f16x8*)(bp0 + cn * 512);
        f16x8 nb1 = *(const f16x8*)(bp1 + cn * 512);
        f32x4 nv0 = *(const f32x4*)(s2p + cn * 32);
        f32x4 nv1 = *(const f32x4*)(s2p + cn * 32 + 4);
        u32 nm = mtp[cn * 2048];

        u32 bits = (xm >> (aq * 8)) & 0xffu;
        f16x8 af;
#pragma unroll
        for (int k = 0; k < 8; ++k) {
            float xv = s1v + (k < 4 ? xv0[k] : xv1[k - 4]);
            float lr = fmaxf(xv, ALPHA_LRELU * xv);
            float bitf = (float)((bits >> k) & 1u);
            float p = EXP2(fmaf(bitf, BIGM, fmaf(lr, LOG2E, C0)));
            lacc += p;
            af[k] = (f16)p;
        }
        acc0 = __builtin_amdgcn_mfma_f32_16x16x32_f16(af, xb0, acc0, 0, 0, 0);
        acc1 = __builtin_amdgcn_mfma_f32_16x16x32_f16(af, xb1, acc1, 0, 0, 0);
        xb0 = nb0; xb1 = nb1; xv0 = nv0; xv1 = nv1; xm = nm;
    }

    // l row sums: lanes sharing am cover disjoint j-slices
    lacc += __shfl_xor(lacc, 16);
    lacc += __shfl_xor(lacc, 32);

#pragma unroll
    for (int e = 0; e < 4; ++e) {
        int r = aq * 4 + e;             // C/D: col=am, row=aq*4+e
        float li = __shfl(lacc, r);     // lane r holds l[row r]
        float v0 = acc0[e] / li, v1 = acc1[e] / li;
        v0 = v0 > 0.f ? v0 : __expf(v0) - 1.f;
        v1 = v1 > 0.f ? v1 : __expf(v1) - 1.f;
        if (OUT) {
            v0 = v0 > 0.f ? v0 : __expf(v0) - 1.f;
            v1 = v1 > 0.f ? v1 : __expf(v1) - 1.f;
        }
        size_t base = ((size_t)b * Nn + i0 + r) * Ff + dstcol;
        dst[base + am] = v0;
        dst[base + 16 + am] = v1;
    }
}

// ---------------------------------------------------------------------------
extern "C" void kernel_launch(void* const* d_in, const int* in_sizes, int n_in,
                              void* d_out, int out_size, void* d_ws, size_t ws_size,
                              hipStream_t stream) {
    const float* x = (const float*)d_in[0];
    const int* adj = (const int*)d_in[1];
    const float* W_heads = (const float*)d_in[2];
    const float* a_heads = (const float*)d_in[3];
    const float* W_out = (const float*)d_in[4];
    const float* a_out = (const float*)d_in[5];
    float* out = (float*)d_out;

    float* ws = (float*)d_ws;
    const size_t M = (size_t)Bc * Nn * Ff;        // 1,048,576
    float* h_cur = ws;                            // M floats
    float* h_tmp = ws + M;                        // M floats
    f16* WhFrag = (f16*)(ws + 2 * M);             // M f16 (M/2 floats)
    f16* Af = (f16*)(ws + 2 * M + M / 2);         // M f16 (M/2 floats)
    u64* maskW = (u64*)(ws + 3 * M);              // 1 MB (M/4 floats)
    u32* maskT = (u32*)(ws + 3 * M + M / 4);      // 1 MB (M/4 floats)
    f16* WTF = (f16*)(ws + 3 * M + M / 2);        // 6*F*F f16 = 196608 floats
    float* sbuf = ws + 3 * M + M / 2 + 196608;
    const size_t SH = (size_t)Bc * Hh * Nn;       // 32768
    const size_t SO = (size_t)Bc * Nn;            // 4096
    const size_t SL = 2 * SH + 2 * SO;

    zero_kernel<<<(3 * SL) / 256, 256, 0, stream>>>(sbuf);
    pack_kernel<<<(Bc * Nn * Nn) / 256, 256, 0, stream>>>(adj, maskW);
    masktr_kernel<<<(Bc * 64 * 2048) / 256, 256, 0, stream>>>((const u32*)maskW, maskT);
    wt_kernel<<<dim3(Ff / 4, 6), 256, 0, stream>>>(W_heads, W_out, WTF);

    for (int l = 0; l < 3; ++l) {
        const float* hin = (l == 0) ? x : h_cur;
        float* s1h = sbuf + l * SL;
        float* s2h = s1h + SH;
        float* s1o = s2h + SH;
        float* s2o = s1o + SO;

        // ---- head GAT: G=8, O=32 ----
        apack_kernel<<<(Bc * Nn * Ff / 8) / 256, 256, 0, stream>>>(hin, Af);
        gemm_wave<<<dim3((Bc * Nn) / 64, Ff / 16), 256, 0, stream>>>(
            Af, WTF + (size_t)(2 * l) * Ff * Ff,
            a_heads + (size_t)l * Hh * 2 * Oo, WhFrag, s1h, s2h, Hh, Oo, 5);
        attn_kernel<false><<<dim3(Nn / 64, 1, Bc * Hh), 256, 0, stream>>>(
            WhFrag, s1h, s2h, maskT, h_tmp);

        // ---- out GAT: G=1, O=F=256 ----
        apack_kernel<<<(Bc * Nn * Ff / 8) / 256, 256, 0, stream>>>(h_tmp, Af);
        gemm_wave<<<dim3((Bc * Nn) / 64, Ff / 16), 256, 0, stream>>>(
            Af, WTF + (size_t)(2 * l + 1) * Ff * Ff,
            a_out + (size_t)l * 2 * Ff, WhFrag, s1o, s2o, 1, Ff, 8);
        float* dstp = (l == 2) ? out : h_cur;
        attn_kernel<true><<<dim3(Nn / 64, Ff / 32, Bc), 256, 0, stream>>>(
            WhFrag, s1o, s2o, maskT, dstp);
    }
}

// Round 11
// 309.233 us; speedup vs baseline: 1.7431x; 1.0562x over previous
//
#include <hip/hip_runtime.h>
#include <math.h>

#if __has_builtin(__builtin_amdgcn_exp2f)
#define EXP2(x) __builtin_amdgcn_exp2f(x)
#else
#define EXP2(x) exp2f(x)
#endif

#define ALPHA_LRELU 0.2f
#define LOG2E 1.4426950408889634f
#define ESHIFT 6.0f
#define BIGM 1024.0f  // bit=0 -> exp2 arg < -1000 -> p = 0

constexpr int Bc = 2, Nn = 2048, Ff = 256, Hh = 8, Oo = 32;

typedef _Float16 f16;
typedef f16 f16x8 __attribute__((ext_vector_type(8)));
typedef f16 f16x4 __attribute__((ext_vector_type(4)));
typedef float f32x4 __attribute__((ext_vector_type(4)));
typedef unsigned long long u64;
typedef unsigned u32;

__global__ __launch_bounds__(256) void zero_kernel(float* __restrict__ p) {
    p[blockIdx.x * 256 + threadIdx.x] = 0.f;
}

// ---------------------------------------------------------------------------
// adj -> bitmask u64 [b][i][c64]
// ---------------------------------------------------------------------------
__global__ __launch_bounds__(256) void pack_kernel(
    const int* __restrict__ adj, u64* __restrict__ mask) {
    int idx = blockIdx.x * 256 + threadIdx.x;
    u64 b = __ballot(adj[idx] != 0);
    if ((threadIdx.x & 63) == 0) mask[idx >> 6] = b;
}

// ---------------------------------------------------------------------------
// mask transpose: maskT[b][c32][i] = maskW32[b][i][c32]
// ---------------------------------------------------------------------------
__global__ __launch_bounds__(256) void masktr_kernel(
    const u32* __restrict__ mw, u32* __restrict__ mt) {
    int idx = blockIdx.x * 256 + threadIdx.x;  // (b*64 + c)*2048 + i
    int i = idx & 2047;
    int c = (idx >> 11) & 63;
    int b = idx >> 17;
    mt[idx] = mw[((size_t)b * 2048 + i) * 64 + c];
}

// ---------------------------------------------------------------------------
// Weights -> B-fragment-packed f16: WTF[y][cg][c][lane*8+i]
// ---------------------------------------------------------------------------
__global__ __launch_bounds__(256) void wt_kernel(
    const float* __restrict__ W_heads, const float* __restrict__ W_out,
    f16* __restrict__ WTF) {
    int t = threadIdx.x;
    int y = blockIdx.y;
    int l = y >> 1, st = y & 1;
    int col = blockIdx.x * 4 + (t >> 6);
    int k0 = (t & 63) * 4;
    const float* src;
    int stride;
    if (st == 0) {
        src = W_heads + (((size_t)l * Hh + (col >> 5)) * Ff) * Oo + (col & 31);
        stride = Oo;
    } else {
        src = W_out + (size_t)l * Ff * Ff + col;
        stride = Ff;
    }
    f16x4 v;
#pragma unroll
    for (int i = 0; i < 4; ++i) v[i] = (f16)src[(size_t)(k0 + i) * stride];
    int cg = col >> 4, am = col & 15;
    int c = k0 >> 5, aq = (k0 >> 3) & 3, i0 = k0 & 7;
    WTF += (((size_t)y * 16 + cg) * 8 + c) * 512 + (aq * 16 + am) * 8 + i0;
    *(f16x4*)WTF = v;
}

// ---------------------------------------------------------------------------
// Activation pack (ONLY for the fp32 input x, once per call):
//   Af[mt][c][lane*8+i] = A[mt*16+am][c*32+aq*8+i]
// ---------------------------------------------------------------------------
__global__ __launch_bounds__(256) void apack_kernel(
    const float* __restrict__ A, f16* __restrict__ Af) {
    int t = threadIdx.x;
    int lane = t & 63;
    int slot = blockIdx.x * 4 + (t >> 6);  // mt*8 + c
    int am = lane & 15, aq = lane >> 4;
    int mt = slot >> 3, c = slot & 7;
    const float* ap = A + ((size_t)mt * 16 + am) * Ff + c * 32 + aq * 8;
    f32x4 v0 = *(const f32x4*)ap;
    f32x4 v1 = *(const f32x4*)(ap + 4);
    f16x8 o;
#pragma unroll
    for (int i = 0; i < 4; ++i) { o[i] = (f16)v0[i]; o[4 + i] = (f16)v1[i]; }
    *(f16x8*)&Af[(size_t)slot * 512 + lane * 8] = o;
}

// ---------------------------------------------------------------------------
// Frag GEMM (unchanged from R9): wave = 16 rows x 16 cols, both operands
// frag-packed (1KB/wave coalesced loads). Epilogue: WhFrag + s1/s2 atomics.
// ---------------------------------------------------------------------------
__global__ __launch_bounds__(256) void gemm_wave(
    const f16* __restrict__ Af, const f16* __restrict__ WTF,
    const float* __restrict__ pa, f16* __restrict__ WhFrag,
    float* __restrict__ s1, float* __restrict__ s2,
    int G, int Ofull, int oshift) {
    int t = threadIdx.x;
    int w = t >> 6, lane = t & 63;
    int am = lane & 15, aq = lane >> 4;
    int mt = blockIdx.x * 4 + w;
    int colb = blockIdx.y * 16;

    const f16* ap = Af + (size_t)(mt * 8) * 512 + lane * 8;
    const f16* bp = WTF + (size_t)((colb >> 4) * 8) * 512 + lane * 8;

    f32x4 acc = {0.f, 0.f, 0.f, 0.f};
    f16x8 a0 = *(const f16x8*)ap;
    f16x8 b0 = *(const f16x8*)bp;
#pragma unroll
    for (int c = 0; c < 8; ++c) {
        int cn = (c + 1 < 8) ? c + 1 : 0;
        f16x8 an = *(const f16x8*)(ap + cn * 512);
        f16x8 bn = *(const f16x8*)(bp + cn * 512);
        acc = __builtin_amdgcn_mfma_f32_16x16x32_f16(a0, b0, acc, 0, 0, 0);
        a0 = an; b0 = bn;
    }

    int m0 = mt * 16;
    int b = m0 >> 11;
    int nn0 = (m0 & 2047) + aq * 4;
    int cO = (m0 & 2047) >> 5;
    int aq_p = ((mt & 1) << 1) | (aq >> 1);
    int i0p = (aq & 1) << 2;
    int g = colb >> oshift;
    size_t bg = (size_t)b * G + g;
    int cg = (colb & (Ofull - 1)) >> 4;

    f16x4 c4;
#pragma unroll
    for (int e = 0; e < 4; ++e) c4[e] = (f16)acc[e];
    *(f16x4*)&WhFrag[(((bg * (Ofull >> 4) + cg) * 64 + cO) * 512) +
                     (aq_p * 16 + am) * 8 + i0p] = c4;

    int o0 = (colb & (Ofull - 1)) + am;
    const float* a1p = pa + 2 * (size_t)g * Ofull;
    float a10 = a1p[o0];
    float a20 = a1p[Ofull + o0];
#pragma unroll
    for (int e = 0; e < 4; ++e) {
        float p1 = acc[e] * a10;
        float p2 = acc[e] * a20;
#pragma unroll
        for (int s = 1; s < 16; s <<= 1) {
            p1 += __shfl_xor(p1, s);
            p2 += __shfl_xor(p2, s);
        }
        if (am == 0) {
            size_t sidx = bg * Nn + nn0 + e;
            atomicAdd(&s1[sidx], p1);
            atomicAdd(&s2[sidx], p2);
        }
    }
}

// ---------------------------------------------------------------------------
// Attention: e-in-registers, coalesced frag loads (R9 hot loop, unchanged).
// Fused epilogue: non-FINAL writes the next stage's A-frag f16 directly via
// in-wave LDS transpose. FIX vs R10: Af tile index uses the GLOBAL row
// (b*Nn + i0), not the per-batch row i0.
// ---------------------------------------------------------------------------
template <bool OUT, bool FINAL>
__global__ __launch_bounds__(256) void attn_kernel(
    const f16* __restrict__ WhFrag, const float* __restrict__ s1,
    const float* __restrict__ s2, const u32* __restrict__ maskT,
    float* __restrict__ dst, f16* __restrict__ AfOut) {
    constexpr float C0 = -ESHIFT * LOG2E - BIGM;
    constexpr int NCG = OUT ? 16 : 2;
    constexpr int TSTR = 40;  // f16 LDS row stride (80B: 16B-aligned, 2-way banks)
    __shared__ f16 T[4][16 * TSTR];

    int t = threadIdx.x;
    int w = t >> 6, lane = t & 63;
    int am = lane & 15, aq = lane >> 4;
    int i0 = blockIdx.x * 64 + w * 16;
    int bz = blockIdx.z;
    int b = OUT ? bz : (bz >> 3);
    int cg0 = OUT ? blockIdx.y * 2 : 0;
    int dstcol = OUT ? cg0 * 16 : (bz & 7) * Oo;

    const f16* bp0 = WhFrag + ((size_t)bz * NCG + cg0) * 64 * 512 + lane * 8;
    const f16* bp1 = bp0 + 64 * 512;
    const float* s2p = s2 + (size_t)bz * Nn + aq * 8;
    float s1v = s1[(size_t)bz * Nn + i0 + am];
    const u32* mtp = maskT + (size_t)b * 64 * 2048 + i0 + am;

    f32x4 acc0 = {0.f, 0.f, 0.f, 0.f}, acc1 = acc0;
    float lacc = 0.f;

    f16x8 xb0 = *(const f16x8*)bp0;
    f16x8 xb1 = *(const f16x8*)bp1;
    f32x4 xv0 = *(const f32x4*)s2p;
    f32x4 xv1 = *(const f32x4*)(s2p + 4);
    u32 xm = mtp[0];

    for (int c = 0; c < 64; ++c) {
        int cn = (c + 1 < 64) ? c + 1 : 0;
        f16x8 nb0 = *(const f16x8*)(bp0 + cn * 512);
        f16x8 nb1 = *(const f16x8*)(bp1 + cn * 512);
        f32x4 nv0 = *(const f32x4*)(s2p + cn * 32);
        f32x4 nv1 = *(const f32x4*)(s2p + cn * 32 + 4);
        u32 nm = mtp[cn * 2048];

        u32 bits = (xm >> (aq * 8)) & 0xffu;
        f16x8 af;
#pragma unroll
        for (int k = 0; k < 8; ++k) {
            float xv = s1v + (k < 4 ? xv0[k] : xv1[k - 4]);
            float lr = fmaxf(xv, ALPHA_LRELU * xv);
            float bitf = (float)((bits >> k) & 1u);
            float p = EXP2(fmaf(bitf, BIGM, fmaf(lr, LOG2E, C0)));
            lacc += p;
            af[k] = (f16)p;
        }
        acc0 = __builtin_amdgcn_mfma_f32_16x16x32_f16(af, xb0, acc0, 0, 0, 0);
        acc1 = __builtin_amdgcn_mfma_f32_16x16x32_f16(af, xb1, acc1, 0, 0, 0);
        xb0 = nb0; xb1 = nb1; xv0 = nv0; xv1 = nv1; xm = nm;
    }

    // l row sums
    lacc += __shfl_xor(lacc, 16);
    lacc += __shfl_xor(lacc, 32);

    f16* Tw = T[w];
#pragma unroll
    for (int e = 0; e < 4; ++e) {
        int r = aq * 4 + e;             // C/D: col=am, row=aq*4+e
        float li = __shfl(lacc, r);
        float v0 = acc0[e] / li, v1 = acc1[e] / li;
        v0 = v0 > 0.f ? v0 : __expf(v0) - 1.f;
        v1 = v1 > 0.f ? v1 : __expf(v1) - 1.f;
        if (OUT) {
            v0 = v0 > 0.f ? v0 : __expf(v0) - 1.f;
            v1 = v1 > 0.f ? v1 : __expf(v1) - 1.f;
        }
        if (FINAL) {
            size_t base = ((size_t)b * Nn + i0 + r) * Ff + dstcol;
            dst[base + am] = v0;
            dst[base + 16 + am] = v1;
        } else {
            Tw[r * TSTR + am] = (f16)v0;
            Tw[r * TSTR + 16 + am] = (f16)v1;
        }
    }
    if (!FINAL) {
        // in-wave read-back in A-frag order (no barrier: same wave's data)
        f16x8 o = *(const f16x8*)&Tw[am * TSTR + aq * 8];
        int mt = (b * Nn + i0) >> 4;   // GLOBAL row tile (fix vs R10)
        int c = dstcol >> 5;
        *(f16x8*)&AfOut[(size_t)(mt * 8 + c) * 512 + lane * 8] = o;
    }
}

// ---------------------------------------------------------------------------
extern "C" void kernel_launch(void* const* d_in, const int* in_sizes, int n_in,
                              void* d_out, int out_size, void* d_ws, size_t ws_size,
                              hipStream_t stream) {
    const float* x = (const float*)d_in[0];
    const int* adj = (const int*)d_in[1];
    const float* W_heads = (const float*)d_in[2];
    const float* a_heads = (const float*)d_in[3];
    const float* W_out = (const float*)d_in[4];
    const float* a_out = (const float*)d_in[5];
    float* out = (float*)d_out;

    float* ws = (float*)d_ws;
    const size_t M = (size_t)Bc * Nn * Ff;        // 1,048,576
    f16* Af_a = (f16*)ws;                         // M f16
    f16* Af_b = (f16*)(ws + M / 2);               // M f16
    f16* WhFrag = (f16*)(ws + M);                 // M f16
    u64* maskW = (u64*)(ws + 3 * M / 2);          // 1 MB
    u32* maskT = (u32*)(ws + 3 * M / 2 + M / 4);  // 1 MB
    f16* WTF = (f16*)(ws + 3 * M / 2 + M / 2);    // 6*F*F f16 = 196608 floats
    float* sbuf = ws + 3 * M / 2 + M / 2 + 196608;
    const size_t SH = (size_t)Bc * Hh * Nn;       // 32768
    const size_t SO = (size_t)Bc * Nn;            // 4096
    const size_t SL = 2 * SH + 2 * SO;

    zero_kernel<<<(3 * SL) / 256, 256, 0, stream>>>(sbuf);
    pack_kernel<<<(Bc * Nn * Nn) / 256, 256, 0, stream>>>(adj, maskW);
    masktr_kernel<<<(Bc * 64 * 2048) / 256, 256, 0, stream>>>((const u32*)maskW, maskT);
    wt_kernel<<<dim3(Ff / 4, 6), 256, 0, stream>>>(W_heads, W_out, WTF);
    apack_kernel<<<(Bc * Nn * Ff / 8) / 256, 256, 0, stream>>>(x, Af_a);

    for (int l = 0; l < 3; ++l) {
        float* s1h = sbuf + l * SL;
        float* s2h = s1h + SH;
        float* s1o = s2h + SH;
        float* s2o = s1o + SO;

        // ---- head GAT: G=8, O=32 ----
        gemm_wave<<<dim3((Bc * Nn) / 64, Ff / 16), 256, 0, stream>>>(
            Af_a, WTF + (size_t)(2 * l) * Ff * Ff,
            a_heads + (size_t)l * Hh * 2 * Oo, WhFrag, s1h, s2h, Hh, Oo, 5);
        attn_kernel<false, false><<<dim3(Nn / 64, 1, Bc * Hh), 256, 0, stream>>>(
            WhFrag, s1h, s2h, maskT, nullptr, Af_b);

        // ---- out GAT: G=1, O=F=256 ----
        gemm_wave<<<dim3((Bc * Nn) / 64, Ff / 16), 256, 0, stream>>>(
            Af_b, WTF + (size_t)(2 * l + 1) * Ff * Ff,
            a_out + (size_t)l * 2 * Ff, WhFrag, s1o, s2o, 1, Ff, 8);
        if (l == 2) {
            attn_kernel<true, true><<<dim3(Nn / 64, Ff / 32, Bc), 256, 0, stream>>>(
                WhFrag, s1o, s2o, maskT, out, nullptr);
        } else {
            attn_kernel<true, false><<<dim3(Nn / 64, Ff / 32, Bc), 256, 0, stream>>>(
                WhFrag, s1o, s2o, maskT, nullptr, Af_a);
        }
    }
}

// Round 12
// 301.694 us; speedup vs baseline: 1.7867x; 1.0250x over previous
//
#include <hip/hip_runtime.h>
#include <math.h>

#if __has_builtin(__builtin_amdgcn_exp2f)
#define EXP2(x) __builtin_amdgcn_exp2f(x)
#else
#define EXP2(x) exp2f(x)
#endif

#define ALPHA_LRELU 0.2f
#define LOG2E 1.4426950408889634f
#define ESHIFT 6.0f
#define BIGM 1024.0f  // bit=0 -> exp2 arg < -1000 -> p = 0

constexpr int Bc = 2, Nn = 2048, Ff = 256, Hh = 8, Oo = 32;

typedef _Float16 f16;
typedef f16 f16x8 __attribute__((ext_vector_type(8)));
typedef f16 f16x4 __attribute__((ext_vector_type(4)));
typedef float f32x4 __attribute__((ext_vector_type(4)));
typedef unsigned long long u64;
typedef unsigned u32;

__global__ __launch_bounds__(256) void zero_kernel(float* __restrict__ p) {
    p[blockIdx.x * 256 + threadIdx.x] = 0.f;
}

// ---------------------------------------------------------------------------
// adj -> TRANSPOSED bitmask directly: maskT[b][c32][i] bit k = adj[b][i][c32*32+k]
// (one ballot per wave; lanes 0/1 write the two u32 halves)
// ---------------------------------------------------------------------------
__global__ __launch_bounds__(256) void pack_kernel(
    const int* __restrict__ adj, u32* __restrict__ maskT) {
    int idx = blockIdx.x * 256 + threadIdx.x;
    u64 bl = __ballot(adj[idx] != 0);
    int lane = threadIdx.x & 63;
    int i = (idx >> 11) & 2047;
    int b = idx >> 22;
    int j0 = (idx & 2047) & ~63;  // wave-aligned j base
    int c32 = j0 >> 5;
    if (lane == 0)
        maskT[((size_t)b * 64 + c32) * 2048 + i] = (u32)bl;
    else if (lane == 1)
        maskT[((size_t)b * 64 + c32 + 1) * 2048 + i] = (u32)(bl >> 32);
}

// ---------------------------------------------------------------------------
// Weights -> B-fragment-packed f16: WTF[y][cg][c][lane*8+i]
// ---------------------------------------------------------------------------
__global__ __launch_bounds__(256) void wt_kernel(
    const float* __restrict__ W_heads, const float* __restrict__ W_out,
    f16* __restrict__ WTF) {
    int t = threadIdx.x;
    int y = blockIdx.y;
    int l = y >> 1, st = y & 1;
    int col = blockIdx.x * 4 + (t >> 6);
    int k0 = (t & 63) * 4;
    const float* src;
    int stride;
    if (st == 0) {
        src = W_heads + (((size_t)l * Hh + (col >> 5)) * Ff) * Oo + (col & 31);
        stride = Oo;
    } else {
        src = W_out + (size_t)l * Ff * Ff + col;
        stride = Ff;
    }
    f16x4 v;
#pragma unroll
    for (int i = 0; i < 4; ++i) v[i] = (f16)src[(size_t)(k0 + i) * stride];
    int cg = col >> 4, am = col & 15;
    int c = k0 >> 5, aq = (k0 >> 3) & 3, i0 = k0 & 7;
    WTF += (((size_t)y * 16 + cg) * 8 + c) * 512 + (aq * 16 + am) * 8 + i0;
    *(f16x4*)WTF = v;
}

// ---------------------------------------------------------------------------
// Activation pack (ONLY for the fp32 input x, once per call):
//   Af[mt][c][lane*8+i] = A[mt*16+am][c*32+aq*8+i]
// ---------------------------------------------------------------------------
__global__ __launch_bounds__(256) void apack_kernel(
    const float* __restrict__ A, f16* __restrict__ Af) {
    int t = threadIdx.x;
    int lane = t & 63;
    int slot = blockIdx.x * 4 + (t >> 6);  // mt*8 + c
    int am = lane & 15, aq = lane >> 4;
    int mt = slot >> 3, c = slot & 7;
    const float* ap = A + ((size_t)mt * 16 + am) * Ff + c * 32 + aq * 8;
    f32x4 v0 = *(const f32x4*)ap;
    f32x4 v1 = *(const f32x4*)(ap + 4);
    f16x8 o;
#pragma unroll
    for (int i = 0; i < 4; ++i) { o[i] = (f16)v0[i]; o[4 + i] = (f16)v1[i]; }
    *(f16x8*)&Af[(size_t)slot * 512 + lane * 8] = o;
}

// ---------------------------------------------------------------------------
// Frag GEMM (unchanged from R11): wave = 16 rows x 16 cols, both operands
// frag-packed (1KB/wave coalesced loads). Epilogue: WhFrag + s1/s2 atomics.
// ---------------------------------------------------------------------------
__global__ __launch_bounds__(256) void gemm_wave(
    const f16* __restrict__ Af, const f16* __restrict__ WTF,
    const float* __restrict__ pa, f16* __restrict__ WhFrag,
    float* __restrict__ s1, float* __restrict__ s2,
    int G, int Ofull, int oshift) {
    int t = threadIdx.x;
    int w = t >> 6, lane = t & 63;
    int am = lane & 15, aq = lane >> 4;
    int mt = blockIdx.x * 4 + w;
    int colb = blockIdx.y * 16;

    const f16* ap = Af + (size_t)(mt * 8) * 512 + lane * 8;
    const f16* bp = WTF + (size_t)((colb >> 4) * 8) * 512 + lane * 8;

    f32x4 acc = {0.f, 0.f, 0.f, 0.f};
    f16x8 a0 = *(const f16x8*)ap;
    f16x8 b0 = *(const f16x8*)bp;
#pragma unroll
    for (int c = 0; c < 8; ++c) {
        int cn = (c + 1 < 8) ? c + 1 : 0;
        f16x8 an = *(const f16x8*)(ap + cn * 512);
        f16x8 bn = *(const f16x8*)(bp + cn * 512);
        acc = __builtin_amdgcn_mfma_f32_16x16x32_f16(a0, b0, acc, 0, 0, 0);
        a0 = an; b0 = bn;
    }

    int m0 = mt * 16;
    int b = m0 >> 11;
    int nn0 = (m0 & 2047) + aq * 4;
    int cO = (m0 & 2047) >> 5;
    int aq_p = ((mt & 1) << 1) | (aq >> 1);
    int i0p = (aq & 1) << 2;
    int g = colb >> oshift;
    size_t bg = (size_t)b * G + g;
    int cg = (colb & (Ofull - 1)) >> 4;

    f16x4 c4;
#pragma unroll
    for (int e = 0; e < 4; ++e) c4[e] = (f16)acc[e];
    *(f16x4*)&WhFrag[(((bg * (Ofull >> 4) + cg) * 64 + cO) * 512) +
                     (aq_p * 16 + am) * 8 + i0p] = c4;

    int o0 = (colb & (Ofull - 1)) + am;
    const float* a1p = pa + 2 * (size_t)g * Ofull;
    float a10 = a1p[o0];
    float a20 = a1p[Ofull + o0];
#pragma unroll
    for (int e = 0; e < 4; ++e) {
        float p1 = acc[e] * a10;
        float p2 = acc[e] * a20;
#pragma unroll
        for (int s = 1; s < 16; s <<= 1) {
            p1 += __shfl_xor(p1, s);
            p2 += __shfl_xor(p2, s);
        }
        if (am == 0) {
            size_t sidx = bg * Nn + nn0 + e;
            atomicAdd(&s1[sidx], p1);
            atomicAdd(&s2[sidx], p2);
        }
    }
}

// ---------------------------------------------------------------------------
// Attention, j-split x2 + prefetch-2: block = 4 waves = 2 row-tiles x 2
// j-halves (wr = w&1 row tile, wh = w>>1 j-half of 32 chunks). Coalesced
// frag loads (R9), e-in-registers (R7 math). End: LDS combine of the two
// j-halves (one barrier), waves 0/1 do the epilogue.
// Head grid (64,1,16); Out grid (64,8,2) -> 1024 blocks = 4 waves/SIMD.
// ---------------------------------------------------------------------------
template <bool OUT, bool FINAL>
__global__ __launch_bounds__(256) void attn_kernel(
    const f16* __restrict__ WhFrag, const float* __restrict__ s1,
    const float* __restrict__ s2, const u32* __restrict__ maskT,
    float* __restrict__ dst, f16* __restrict__ AfOut) {
    constexpr float C0 = -ESHIFT * LOG2E - BIGM;
    constexpr int NCG = OUT ? 16 : 2;
    constexpr int TSTR = 40;
    __shared__ float Ls[4][64];
    __shared__ float As[4][64][8];
    __shared__ f16 T[2][16 * TSTR];

    int t = threadIdx.x;
    int w = t >> 6, lane = t & 63;
    int am = lane & 15, aq = lane >> 4;
    int wr = w & 1;   // row tile within block
    int wh = w >> 1;  // j half
    int i0 = blockIdx.x * 32 + wr * 16;
    int bz = blockIdx.z;
    int b = OUT ? bz : (bz >> 3);
    int cg0 = OUT ? blockIdx.y * 2 : 0;
    int dstcol = OUT ? cg0 * 16 : (bz & 7) * Oo;

    const f16* bp0 = WhFrag + ((size_t)bz * NCG + cg0) * 64 * 512 + lane * 8;
    const f16* bp1 = bp0 + 64 * 512;
    const float* s2p = s2 + (size_t)bz * Nn + aq * 8;
    float s1v = s1[(size_t)bz * Nn + i0 + am];
    const u32* mtp = maskT + (size_t)b * 64 * 2048 + i0 + am;

    f32x4 acc0 = {0.f, 0.f, 0.f, 0.f}, acc1 = acc0;
    float lacc = 0.f;

    int cbeg = wh * 32, cend = cbeg + 32;

    f16x8 xb0, xb1, yb0, yb1;
    f32x4 xv0, xv1, yv0, yv1;
    u32 xm, ym;
    auto ld = [&](int c, f16x8& b0, f16x8& b1, f32x4& v0, f32x4& v1, u32& m) {
        b0 = *(const f16x8*)(bp0 + c * 512);
        b1 = *(const f16x8*)(bp1 + c * 512);
        v0 = *(const f32x4*)(s2p + c * 32);
        v1 = *(const f32x4*)(s2p + c * 32 + 4);
        m = mtp[c * 2048];
    };
    auto comp = [&](f16x8 b0, f16x8 b1, f32x4 v0, f32x4 v1, u32 m) {
        u32 bits = (m >> (aq * 8)) & 0xffu;
        f16x8 af;
#pragma unroll
        for (int k = 0; k < 8; ++k) {
            float xv = s1v + (k < 4 ? v0[k] : v1[k - 4]);
            float lr = fmaxf(xv, ALPHA_LRELU * xv);
            float bitf = (float)((bits >> k) & 1u);
            float p = EXP2(fmaf(bitf, BIGM, fmaf(lr, LOG2E, C0)));
            lacc += p;
            af[k] = (f16)p;
        }
        acc0 = __builtin_amdgcn_mfma_f32_16x16x32_f16(af, b0, acc0, 0, 0, 0);
        acc1 = __builtin_amdgcn_mfma_f32_16x16x32_f16(af, b1, acc1, 0, 0, 0);
    };

    ld(cbeg, xb0, xb1, xv0, xv1, xm);
    ld(cbeg + 1, yb0, yb1, yv0, yv1, ym);
    for (int c = cbeg; c < cend; c += 2) {
        comp(xb0, xb1, xv0, xv1, xm);
        ld(c + 2 < cend ? c + 2 : cbeg, xb0, xb1, xv0, xv1, xm);
        comp(yb0, yb1, yv0, yv1, ym);
        ld(c + 3 < cend ? c + 3 : cbeg, yb0, yb1, yv0, yv1, ym);
    }

    // intra-wave l: sum over aq groups -> lane holds l_half[am]
    lacc += __shfl_xor(lacc, 16);
    lacc += __shfl_xor(lacc, 32);

    // cross-wave combine of the two j-halves
    Ls[w][lane] = lacc;
#pragma unroll
    for (int e = 0; e < 4; ++e) {
        As[w][lane][e] = acc0[e];
        As[w][lane][4 + e] = acc1[e];
    }
    __syncthreads();

    if (wh == 0) {
        float lt = Ls[w][lane] + Ls[w + 2][lane];
        f32x4 a0, a1;
#pragma unroll
        for (int e = 0; e < 4; ++e) {
            a0[e] = As[w][lane][e] + As[w + 2][lane][e];
            a1[e] = As[w][lane][4 + e] + As[w + 2][lane][4 + e];
        }
        f16* Tw = T[wr];
#pragma unroll
        for (int e = 0; e < 4; ++e) {
            int r = aq * 4 + e;             // C/D: col=am, row=aq*4+e
            float li = __shfl(lt, r);       // lane r holds l[row r]
            float v0 = a0[e] / li, v1 = a1[e] / li;
            v0 = v0 > 0.f ? v0 : __expf(v0) - 1.f;
            v1 = v1 > 0.f ? v1 : __expf(v1) - 1.f;
            if (OUT) {
                v0 = v0 > 0.f ? v0 : __expf(v0) - 1.f;
                v1 = v1 > 0.f ? v1 : __expf(v1) - 1.f;
            }
            if (FINAL) {
                size_t base = ((size_t)b * Nn + i0 + r) * Ff + dstcol;
                dst[base + am] = v0;
                dst[base + 16 + am] = v1;
            } else {
                Tw[r * TSTR + am] = (f16)v0;
                Tw[r * TSTR + 16 + am] = (f16)v1;
            }
        }
        if (!FINAL) {
            // in-wave read-back in A-frag order (no barrier: same wave's data)
            f16x8 o = *(const f16x8*)&Tw[am * TSTR + aq * 8];
            int mt = (b * Nn + i0) >> 4;   // GLOBAL row tile
            int c = dstcol >> 5;
            *(f16x8*)&AfOut[(size_t)(mt * 8 + c) * 512 + lane * 8] = o;
        }
    }
}

// ---------------------------------------------------------------------------
extern "C" void kernel_launch(void* const* d_in, const int* in_sizes, int n_in,
                              void* d_out, int out_size, void* d_ws, size_t ws_size,
                              hipStream_t stream) {
    const float* x = (const float*)d_in[0];
    const int* adj = (const int*)d_in[1];
    const float* W_heads = (const float*)d_in[2];
    const float* a_heads = (const float*)d_in[3];
    const float* W_out = (const float*)d_in[4];
    const float* a_out = (const float*)d_in[5];
    float* out = (float*)d_out;

    float* ws = (float*)d_ws;
    const size_t M = (size_t)Bc * Nn * Ff;        // 1,048,576
    f16* Af_a = (f16*)ws;                         // M f16
    f16* Af_b = (f16*)(ws + M / 2);               // M f16
    f16* WhFrag = (f16*)(ws + M);                 // M f16
    u32* maskT = (u32*)(ws + 3 * M / 2);          // 1 MB (M/4 floats)
    f16* WTF = (f16*)(ws + 3 * M / 2 + M / 4);    // 6*F*F f16 = 196608 floats
    float* sbuf = ws + 3 * M / 2 + M / 4 + 196608;
    const size_t SH = (size_t)Bc * Hh * Nn;       // 32768
    const size_t SO = (size_t)Bc * Nn;            // 4096
    const size_t SL = 2 * SH + 2 * SO;

    zero_kernel<<<(3 * SL) / 256, 256, 0, stream>>>(sbuf);
    pack_kernel<<<(Bc * Nn * Nn) / 256, 256, 0, stream>>>(adj, maskT);
    wt_kernel<<<dim3(Ff / 4, 6), 256, 0, stream>>>(W_heads, W_out, WTF);
    apack_kernel<<<(Bc * Nn * Ff / 8) / 256, 256, 0, stream>>>(x, Af_a);

    for (int l = 0; l < 3; ++l) {
        float* s1h = sbuf + l * SL;
        float* s2h = s1h + SH;
        float* s1o = s2h + SH;
        float* s2o = s1o + SO;

        // ---- head GAT: G=8, O=32 ----
        gemm_wave<<<dim3((Bc * Nn) / 64, Ff / 16), 256, 0, stream>>>(
            Af_a, WTF + (size_t)(2 * l) * Ff * Ff,
            a_heads + (size_t)l * Hh * 2 * Oo, WhFrag, s1h, s2h, Hh, Oo, 5);
        attn_kernel<false, false><<<dim3(Nn / 32, 1, Bc * Hh), 256, 0, stream>>>(
            WhFrag, s1h, s2h, maskT, nullptr, Af_b);

        // ---- out GAT: G=1, O=F=256 ----
        gemm_wave<<<dim3((Bc * Nn) / 64, Ff / 16), 256, 0, stream>>>(
            Af_b, WTF + (size_t)(2 * l + 1) * Ff * Ff,
            a_out + (size_t)l * 2 * Ff, WhFrag, s1o, s2o, 1, Ff, 8);
        if (l == 2) {
            attn_kernel<true, true><<<dim3(Nn / 32, Ff / 32, Bc), 256, 0, stream>>>(
                WhFrag, s1o, s2o, maskT, out, nullptr);
        } else {
            attn_kernel<true, false><<<dim3(Nn / 32, Ff / 32, Bc), 256, 0, stream>>>(
                WhFrag, s1o, s2o, maskT, nullptr, Af_a);
        }
    }
}